// Round 11
// baseline (44.398 us; speedup 1.0000x reference)
//
#include <hip/hip_runtime.h>
#include <hip/hip_bf16.h>
#include <math.h>

#define NB   32
#define CIN  4
#define COUT 64
#define TT   6
#define VV   512
#define NROW 24                 // c*6+t rows of x per batch
#define P_OFF (NB*COUT*TT*VV)   // out then p in d_out

typedef __attribute__((ext_vector_type(8))) short bf16x8;
typedef __attribute__((ext_vector_type(4))) float f32x4;

__device__ inline unsigned int pack2(float a, float b) {
    __hip_bfloat162 h = __float22bfloat162_rn(make_float2(a, b));
    return *reinterpret_cast<unsigned int*>(&h);
}

// ---------------------------------------------------------------------------
// Pass 1: per block (sr, n): compute e_i/e_j (x is tiny/L2), then for 16 rows
// i = sr*16..+15: read mask row A[n,7,i,:], emit bitmask row (64 B),
// rowdat[n*512+i] = (e_i, rowmax, 1/rowsum, 0). Block sr==0 writes e_j+l1b.
// 1024 blocks -> 4/CU; mask stream is the only HBM read (33.5 MB).
// ---------------------------------------------------------------------------
__global__ __launch_bounds__(256, 2) void pass1_kernel(
    const float* __restrict__ x,
    const int*   __restrict__ A,
    const float* __restrict__ conv_w,
    const float* __restrict__ conv_b,
    const float* __restrict__ l2_w,
    const float* __restrict__ l2_b,
    const float* __restrict__ l1_w,
    const float* __restrict__ l1_b,
    float*       __restrict__ ejw,      // e_j + l1b, [NB][VV]
    float4*      __restrict__ rowdat,   // (e_i, mx, inv, 0) per row
    unsigned char* __restrict__ bm)     // bitmask, 64 B per row
{
    __shared__ float W1s[CIN], W2s[CIN], cst[2], l2s[TT];
    __shared__ float ejl[VV];           // e_j + cst1 + l1b
    __shared__ float eil[VV];           // e_i (incl cst0)

    int sr = blockIdx.x;                // 32 row-groups of 16
    int n  = blockIdx.y;
    int tid = threadIdx.x;
    int lane = tid & 63;
    int wave = tid >> 6;

    if (tid < CIN) {
        float w1 = 0.f, w2 = 0.f;
        for (int o = 0; o < COUT; ++o) {
            w1 += l1_w[o]        * conv_w[o*CIN + tid];
            w2 += l1_w[COUT + o] * conv_w[o*CIN + tid];
        }
        W1s[tid] = w1; W2s[tid] = w2;
    }
    if (tid < TT) l2s[tid] = l2_w[tid];
    if (tid == CIN) {
        float B1 = 0.f, B2 = 0.f, S1 = 0.f, S2 = 0.f;
        for (int o = 0; o < COUT; ++o) {
            B1 += l1_w[o]        * conv_b[o];
            B2 += l1_w[COUT + o] * conv_b[o];
            S1 += l1_w[o];
            S2 += l1_w[COUT + o];
        }
        float Ls = 0.f;
        for (int t = 0; t < TT; ++t) Ls += l2_w[t];
        cst[0] = Ls*B1 + l2_b[0]*S1;
        cst[1] = Ls*B2 + l2_b[0]*S2 + l1_b[0];    // fold l1_b into e_j
    }
    __syncthreads();

    // e_i / e_j for 2 j's per thread (x reads coalesced float2)
    {
        int j0 = tid*2;
        float ej0 = cst[1], ej1 = cst[1], ei0 = cst[0], ei1 = cst[0];
        #pragma unroll
        for (int c = 0; c < CIN; ++c) {
            float w1 = W1s[c], w2 = W2s[c];
            #pragma unroll
            for (int t = 0; t < TT; ++t) {
                float lw = l2s[t];
                float2 xv = *(const float2*)&x[((size_t)(n*CIN + c)*TT + t)*VV + j0];
                float a1 = lw*w1, a2 = lw*w2;
                ei0 = fmaf(a1, xv.x, ei0); ei1 = fmaf(a1, xv.y, ei1);
                ej0 = fmaf(a2, xv.x, ej0); ej1 = fmaf(a2, xv.y, ej1);
            }
        }
        ejl[j0] = ej0; ejl[j0+1] = ej1;
        eil[j0] = ei0; eil[j0+1] = ei1;
        if (sr == 0) {
            float* eo = ejw + (size_t)n*VV + j0;
            eo[0] = ej0; eo[1] = ej1;
        }
    }
    __syncthreads();

    float ejv[8];
    #pragma unroll
    for (int m = 0; m < 8; ++m) ejv[m] = ejl[lane*8 + m];

    for (int it = 0; it < 4; ++it) {
        int i = sr*16 + it*4 + wave;
        const int* mr = A + (((size_t)(n*8 + 7)*VV + i))*VV + lane*8;
        int4 a0 = *(const int4*)mr;
        int4 a1 = *(const int4*)(mr + 4);
        int mk[8] = {a0.x,a0.y,a0.z,a0.w, a1.x,a1.y,a1.z,a1.w};

        float ei = eil[i];
        float sv[8];
        unsigned int byte = 0u;
        #pragma unroll
        for (int m = 0; m < 8; ++m) {
            float t = ei + ejv[m];
            t = (t >= 0.f) ? t : 0.2f*t;
            unsigned int on = (mk[m] != 0) ? 1u : 0u;
            byte |= on << m;
            sv[m] = on ? t : -INFINITY;
        }
        float mx = sv[0];
        #pragma unroll
        for (int m = 1; m < 8; ++m) mx = fmaxf(mx, sv[m]);
        #pragma unroll
        for (int off = 32; off; off >>= 1) mx = fmaxf(mx, __shfl_xor(mx, off));

        float sum = 0.f;
        if (mx > -INFINITY) {
            #pragma unroll
            for (int m = 0; m < 8; ++m) sum += __expf(sv[m] - mx);
        }
        #pragma unroll
        for (int off = 32; off; off >>= 1) sum += __shfl_xor(sum, off);

        float mxs, invv;
        if (mx > -INFINITY) { mxs = mx; invv = 1.f/sum; }
        else                { mxs = 0.f; invv = 0.f; }

        bm[((size_t)(n*VV + i))*64 + lane] = (unsigned char)byte;
        if (lane == 0)
            rowdat[(size_t)n*VV + i] = make_float4(ei, mxs, invv, 0.f);
    }
}

// ---------------------------------------------------------------------------
// Pass 2: per block (wc, n): owns w in [wc*32, wc*32+32). For all 512 i:
// p[i][w] = bit ? exp(lrelu-score - mx[i])*inv[i] : 0 (elementwise, rowdat).
// Writes p (f32, via LDS transpose), accumulates y[32][32] with
// mfma_f32_16x16x32_bf16 over K=512 (x as bf16-pair LDS, R9-verified map),
// then applies conv expansion and writes out directly. No ypart.
// ---------------------------------------------------------------------------
__global__ __launch_bounds__(256, 2) void pass2_kernel(
    const float* __restrict__ x,
    const unsigned int* __restrict__ bm32,
    const float* __restrict__ ejw,
    const float4* __restrict__ rowdat,
    const float* __restrict__ conv_w,
    const float* __restrict__ conv_b,
    float*       __restrict__ p,
    float*       __restrict__ out)
{
    __shared__ unsigned int xa[256][33];          // bf16-pair x, [ip][r] 33.8 KB
    __shared__ unsigned int pk[2][32][34];        // bf16-pair p tile, dbuf 8.7 KB
    __shared__ __align__(16) float ps[2][64][36]; // f32 p tile, dbuf 18.4 KB
    __shared__ unsigned int bmw[VV];              // 2 KB bit-slices
    __shared__ float4 rd[VV];                     // 8 KB rowdat
    __shared__ float wsm[COUT*CIN];
    __shared__ float bsm[COUT];
    __shared__ float ysm[25][33];

    int wc = blockIdx.x;                 // 16 w-chunks of 32
    int n  = blockIdx.y;
    int tid = threadIdx.x;
    int lane = tid & 63;
    int wave = tid >> 6;                 // 4 waves
    int w    = tid & 31;                 // local w
    int slot = tid >> 5;                 // 8 i-slots
    int mt = wave & 1, nt = wave >> 1;   // MFMA tile of this wave

    // ---- stage x as bf16 pairs: xa[ip][r], r24 = ones, 25..31 = 0 ----
    for (int l = tid; l < 32*256; l += 256) {
        int ip = l & 255, r = l >> 8;
        float a = 0.f, b = 0.f;
        if (r < NROW) {
            float2 v = *(const float2*)&x[((size_t)n*NROW + r)*VV + 2*ip];
            a = v.x; b = v.y;
        } else if (r == NROW) { a = 1.f; b = 1.f; }
        xa[ip][r] = pack2(a, b);
    }
    for (int l = tid; l < VV; l += 256) {
        bmw[l] = bm32[((size_t)(n*VV + l))*16 + wc];
        rd[l]  = rowdat[(size_t)n*VV + l];
    }
    if (tid < COUT*CIN) wsm[tid] = conv_w[tid];
    if (tid < COUT)     bsm[tid] = conv_b[tid];
    float biasw = ejw[(size_t)n*VV + wc*32 + w];   // e_j + l1b for this w
    __syncthreads();

    f32x4 acc = {0.f, 0.f, 0.f, 0.f};

    for (int tile = 0; tile < 8; ++tile) {
        int buf = tile & 1;
        int i0  = tile*64;

        // ---- p for 8 i's (thread = (w, slot)) ----
        float pv[8];
        #pragma unroll
        for (int kk = 0; kk < 8; ++kk) {
            int il = i0 + slot*8 + kk;
            float4 r4 = rd[il];                    // (e_i, mx, inv, -)
            float s = r4.x + biasw;
            s = (s >= 0.f) ? s : 0.2f*s;
            float e = __expf(s - r4.y) * r4.z;
            pv[kk] = ((bmw[il] >> w) & 1u) ? e : 0.f;
            ps[buf][slot*8 + kk][w] = pv[kk];
        }
        #pragma unroll
        for (int c = 0; c < 4; ++c)
            pk[buf][slot*4 + c][w] = pack2(pv[2*c], pv[2*c+1]);

        __syncthreads();   // tile ready; also fences reuse of buf from tile-2

        // ---- global p write (transposed through ps) ----
        #pragma unroll
        for (int u = tid; u < 512; u += 256) {
            int r = u >> 3, c4 = u & 7;
            float4 v = *(const float4*)&ps[buf][r][c4*4];
            *(float4*)&p[((size_t)(n*VV) + i0 + r)*VV + wc*32 + c4*4] = v;
        }

        // ---- MFMA: 2 K-groups of 32 i ----
        #pragma unroll
        for (int g = 0; g < 2; ++g) {
            union { unsigned int u[4]; bf16x8 v; } ua, ub;
            #pragma unroll
            for (int jj = 0; jj < 4; ++jj) {
                int ipq = (lane >> 4)*4 + jj;
                ua.u[jj] = xa[tile*32 + g*16 + ipq][mt*16 + (lane & 15)];
                ub.u[jj] = pk[buf][g*16 + ipq][nt*16 + (lane & 15)];
            }
            acc = __builtin_amdgcn_mfma_f32_16x16x32_bf16(ua.v, ub.v, acc, 0, 0, 0);
        }
    }

    // ---- y to LDS: D row = mt*16 + (lane>>4)*4 + reg, col = nt*16+(lane&15)
    __syncthreads();
    #pragma unroll
    for (int reg = 0; reg < 4; ++reg) {
        int row = mt*16 + (lane >> 4)*4 + reg;
        if (row < 25) ysm[row][nt*16 + (lane & 15)] = acc[reg];
    }
    __syncthreads();

    // ---- conv expansion: out[n,o,t,wc*32+w] ----
    float y[25];
    #pragma unroll
    for (int r = 0; r < 25; ++r) y[r] = ysm[r][w];

    int og = tid >> 5;                   // 8 groups x 8 o
    #pragma unroll
    for (int oo = 0; oo < 8; ++oo) {
        int o = og*8 + oo;
        float wb[CIN];
        #pragma unroll
        for (int c = 0; c < CIN; ++c) wb[c] = wsm[o*CIN + c];
        float bo = bsm[o];
        #pragma unroll
        for (int t = 0; t < TT; ++t) {
            float val = bo * y[24];
            #pragma unroll
            for (int c = 0; c < CIN; ++c) val = fmaf(wb[c], y[c*TT + t], val);
            out[((size_t)(n*COUT + o)*TT + t)*VV + wc*32 + w] = val;
        }
    }
}

// ---------------------------------------------------------------------------
extern "C" void kernel_launch(void* const* d_in, const int* in_sizes, int n_in,
                              void* d_out, int out_size, void* d_ws, size_t ws_size,
                              hipStream_t stream)
{
    const float* x      = (const float*)d_in[0];
    const int*   A      = (const int*)  d_in[1];
    const float* conv_w = (const float*)d_in[2];
    const float* conv_b = (const float*)d_in[3];
    const float* l2_w   = (const float*)d_in[4];
    const float* l2_b   = (const float*)d_in[5];
    const float* l1_w   = (const float*)d_in[6];
    const float* l1_b   = (const float*)d_in[7];

    float* out = (float*)d_out;
    float* pP  = out + P_OFF;                       // p region of d_out

    float4* rowdat      = (float4*)d_ws;            // 256 KB
    float*  ejw         = (float*)(rowdat + NB*VV); // 64 KB
    unsigned char* bm   = (unsigned char*)(ejw + NB*VV);  // 1 MB

    dim3 g1(32, NB);                                // 1024 blocks
    pass1_kernel<<<g1, 256, 0, stream>>>(x, A, conv_w, conv_b, l2_w, l2_b,
                                         l1_w, l1_b, ejw, rowdat, bm);

    dim3 g2(16, NB);                                // 512 blocks
    pass2_kernel<<<g2, 256, 0, stream>>>(x, (const unsigned int*)bm, ejw,
                                         rowdat, conv_w, conv_b, pP, out);
}

// Round 12
// 33.634 us; speedup vs baseline: 1.3200x; 1.3200x over previous
//
#include <hip/hip_runtime.h>
#include <hip/hip_bf16.h>
#include <math.h>

#define NB   32
#define CIN  4
#define COUT 64
#define TT   6
#define VV   512
#define P_OFF (NB*COUT*TT*VV)   // out then p in d_out
#define SPLITS 8
#define CH   (VV/SPLITS)        // 64 softmax rows per block
#define NROW 24                 // c*6+t rows of x per batch
#define PKW  516                // pk row stride (u32)

typedef __attribute__((ext_vector_type(8))) short bf16x8;
typedef __attribute__((ext_vector_type(4))) float f32x4;

__device__ inline unsigned int pack2(float a, float b) {
    __hip_bfloat162 h = __float22bfloat162_rn(make_float2(a, b));
    return *reinterpret_cast<unsigned int*>(&h);
}

// ---------------------------------------------------------------------------
// Kernel 1 (fused, MFMA, inline-e): per block (s,n):
//  - compute e_j[0..512) (+l1_b) and e_i for all 512 (keep block's 64) inline
//  - 64 softmax rows -> p (f32 global)
//  - y_part[r][w] = sum_i x[n,r,i]*p[n,i,w] via mfma_f32_16x16x32_bf16
// Structure identical to validated R9 kernel except e comes from LDS.
// ---------------------------------------------------------------------------
__global__ __launch_bounds__(512, 4) void fused_kernel(
    const float* __restrict__ x,
    const int*   __restrict__ A,
    const float* __restrict__ conv_w,
    const float* __restrict__ conv_b,
    const float* __restrict__ l2_w,
    const float* __restrict__ l2_b,
    const float* __restrict__ l1_w,
    const float* __restrict__ l1_b,
    float*       __restrict__ p,
    float*       __restrict__ ypart)
{
    __shared__ float xst[CH][33];            // [i][r], r24 = ones, 25..32 = 0
    __shared__ unsigned int pk[16][PKW];     // bf16-pair stage for one K-group
    __shared__ float W1s[CIN], W2s[CIN], cst[2], l2s[TT];
    __shared__ float ejl[VV];                // e_j + cst1 + l1b
    __shared__ float eil[CH];                // e_i for the block's 64 rows

    int s = blockIdx.x;                  // 8 chunks of 64 rows
    int n = blockIdx.y;
    int tid = threadIdx.x;
    int lane = tid & 63;
    int q = tid >> 6;                    // wave 0..7

    const int* mbase = A + (size_t)(n*8 + 7)*VV*VV;

    // issue sub-0 mask loads immediately (latency covered by e-compute)
    int4 mA0, mA1, mB0, mB1;
    {
        int i0 = s*CH + q*2;
        const int* mr = mbase + (size_t)i0*VV + lane*8;
        mA0 = *(const int4*)mr;       mA1 = *(const int4*)(mr + 4);
        mB0 = *(const int4*)(mr+VV);  mB1 = *(const int4*)(mr + VV + 4);
    }

    // ---- stage tiny weights ----
    if (tid < CIN) {
        float w1 = 0.f, w2 = 0.f;
        for (int o = 0; o < COUT; ++o) {
            w1 += l1_w[o]        * conv_w[o*CIN + tid];
            w2 += l1_w[COUT + o] * conv_w[o*CIN + tid];
        }
        W1s[tid] = w1; W2s[tid] = w2;
    }
    if (tid < TT) l2s[tid] = l2_w[tid];
    if (tid == CIN) {
        float B1 = 0.f, B2 = 0.f, S1 = 0.f, S2 = 0.f;
        for (int o = 0; o < COUT; ++o) {
            B1 += l1_w[o]        * conv_b[o];
            B2 += l1_w[COUT + o] * conv_b[o];
            S1 += l1_w[o];
            S2 += l1_w[COUT + o];
        }
        float Ls = 0.f;
        for (int t = 0; t < TT; ++t) Ls += l2_w[t];
        cst[0] = Ls*B1 + l2_b[0]*S1;
        cst[1] = Ls*B2 + l2_b[0]*S2 + l1_b[0];   // l1_b folded into e_j
    }
    __syncthreads();

    // ---- inline e: thread j computes e_j[j] and e_i[j] (keep if in chunk) --
    {
        int j = tid;
        float ei = cst[0], ej = cst[1];
        #pragma unroll
        for (int c = 0; c < CIN; ++c) {
            float w1 = W1s[c], w2 = W2s[c];
            #pragma unroll
            for (int t = 0; t < TT; ++t) {
                float lw = l2s[t];
                float xv = x[((size_t)(n*CIN + c)*TT + t)*VV + j];
                ei = fmaf(lw*w1, xv, ei);
                ej = fmaf(lw*w2, xv, ej);
            }
        }
        ejl[j] = ej;
        if ((j >> 6) == s) eil[j & 63] = ei;
    }

    // ---- stage xst[i][r] ----
    for (int idx = tid; idx < CH*33; idx += 512) {
        int r = idx >> 6;                // 0..32
        int i = idx & 63;
        float v = 0.f;
        if (r < NROW)       v = x[((size_t)n*NROW + r)*VV + s*CH + i];
        else if (r == NROW) v = 1.f;     // ones-row -> colsum
        xst[i][r] = v;
    }
    __syncthreads();                     // ejl/eil/xst ready

    float ejv[8];
    #pragma unroll
    for (int m = 0; m < 8; ++m) ejv[m] = ejl[lane*8 + m];

    f32x4 acc[2][4];
    #pragma unroll
    for (int mt = 0; mt < 2; ++mt)
        #pragma unroll
        for (int t = 0; t < 4; ++t) acc[mt][t] = (f32x4){0.f, 0.f, 0.f, 0.f};

    bf16x8 afr[2][2];                    // [Kgroup][mtile]

    for (int sub = 0; sub < 4; ++sub) {
        int ilA  = sub*16 + q*2;
        int i_gA = s*CH + ilA;

        int4 cA0 = mA0, cA1 = mA1, cB0 = mB0, cB1 = mB1;
        float biasA = eil[ilA], biasB = eil[ilA + 1];

        if (sub < 3) {                   // prefetch next sub's masks
            const int* mr = mbase + (size_t)(i_gA + 16)*VV + lane*8;
            mA0 = *(const int4*)mr;       mA1 = *(const int4*)(mr + 4);
            mB0 = *(const int4*)(mr+VV);  mB1 = *(const int4*)(mr + VV + 4);
        }

        // ---- softmax rows A & B (j = lane*8 + m) ----
        float svA[8], svB[8];
        int mkA[8] = {cA0.x,cA0.y,cA0.z,cA0.w, cA1.x,cA1.y,cA1.z,cA1.w};
        int mkB[8] = {cB0.x,cB0.y,cB0.z,cB0.w, cB1.x,cB1.y,cB1.z,cB1.w};
        #pragma unroll
        for (int m2 = 0; m2 < 8; ++m2) {
            float tA = biasA + ejv[m2]; tA = (tA >= 0.f) ? tA : 0.2f*tA;
            svA[m2] = (mkA[m2] == 0) ? -INFINITY : tA;
            float tB = biasB + ejv[m2]; tB = (tB >= 0.f) ? tB : 0.2f*tB;
            svB[m2] = (mkB[m2] == 0) ? -INFINITY : tB;
        }
        float mA = svA[0], mB = svB[0];
        #pragma unroll
        for (int m2 = 1; m2 < 8; ++m2) {
            mA = fmaxf(mA, svA[m2]); mB = fmaxf(mB, svB[m2]);
        }
        #pragma unroll
        for (int off = 32; off; off >>= 1) {
            mA = fmaxf(mA, __shfl_xor(mA, off));
            mB = fmaxf(mB, __shfl_xor(mB, off));
        }
        float sumA = 0.f, sumB = 0.f;
        if (mA > -INFINITY) {
            #pragma unroll
            for (int m2 = 0; m2 < 8; ++m2) { svA[m2] = __expf(svA[m2]-mA); sumA += svA[m2]; }
        } else {
            #pragma unroll
            for (int m2 = 0; m2 < 8; ++m2) svA[m2] = 0.f;
        }
        if (mB > -INFINITY) {
            #pragma unroll
            for (int m2 = 0; m2 < 8; ++m2) { svB[m2] = __expf(svB[m2]-mB); sumB += svB[m2]; }
        } else {
            #pragma unroll
            for (int m2 = 0; m2 < 8; ++m2) svB[m2] = 0.f;
        }
        #pragma unroll
        for (int off = 32; off; off >>= 1) {
            sumA += __shfl_xor(sumA, off);
            sumB += __shfl_xor(sumB, off);
        }
        float invA = (sumA > 0.f) ? 1.f/sumA : 0.f;
        float invB = (sumB > 0.f) ? 1.f/sumB : 0.f;
        #pragma unroll
        for (int m2 = 0; m2 < 8; ++m2) { svA[m2] *= invA; svB[m2] *= invB; }

        // global p stores (f32 exact, 16B/lane coalesced)
        float* prA = p + ((size_t)(n*VV + i_gA))*VV + lane*8;
        float4 pA03 = {svA[0],svA[1],svA[2],svA[3]}, pA47 = {svA[4],svA[5],svA[6],svA[7]};
        float4 pB03 = {svB[0],svB[1],svB[2],svB[3]}, pB47 = {svB[4],svB[5],svB[6],svB[7]};
        *(float4*)prA            = pA03;
        *(float4*)(prA + 4)      = pA47;
        *(float4*)(prA + VV)     = pB03;
        *(float4*)(prA + VV + 4) = pB47;

        // pk store: pair-row = (sub&1)*8 + q
        {
            int pr = (sub & 1)*8 + q;
            uint4 u0 = {pack2(svA[0],svB[0]), pack2(svA[1],svB[1]),
                        pack2(svA[2],svB[2]), pack2(svA[3],svB[3])};
            uint4 u1 = {pack2(svA[4],svB[4]), pack2(svA[5],svB[5]),
                        pack2(svA[6],svB[6]), pack2(svA[7],svB[7])};
            *(uint4*)&pk[pr][lane*8]     = u0;
            *(uint4*)&pk[pr][lane*8 + 4] = u1;
        }

        if (sub & 1) {
            __syncthreads();             // K-group pk complete

            if (sub == 1) {
                // build A-frags: k = g*32 + (lane>>4)*8 + j, m = mt*16+(lane&15)
                #pragma unroll
                for (int g = 0; g < 2; ++g)
                    #pragma unroll
                    for (int mt = 0; mt < 2; ++mt) {
                        int r  = mt*16 + (lane & 15);
                        int kb = g*32 + (lane >> 4)*8;
                        union { unsigned int u[4]; bf16x8 v; } ua;
                        #pragma unroll
                        for (int t = 0; t < 4; ++t)
                            ua.u[t] = pack2(xst[kb + 2*t][r], xst[kb + 2*t + 1][r]);
                        afr[g][mt] = ua.v;
                    }
            }

            int g = sub >> 1;            // K-group 0 or 1
            #pragma unroll
            for (int t = 0; t < 4; ++t) {
                int ncol = (q*4 + t)*16 + (lane & 15);
                union { unsigned int u[4]; bf16x8 v; } ub;
                #pragma unroll
                for (int jj = 0; jj < 4; ++jj)
                    ub.u[jj] = pk[(lane >> 4)*4 + jj][ncol];
                acc[0][t] = __builtin_amdgcn_mfma_f32_16x16x32_bf16(afr[g][0], ub.v, acc[0][t], 0, 0, 0);
                acc[1][t] = __builtin_amdgcn_mfma_f32_16x16x32_bf16(afr[g][1], ub.v, acc[1][t], 0, 0, 0);
            }
            if (sub == 1) __syncthreads();   // MFMA g0 done before sub2 overwrites pk
        }
    }

    // ---- write ypart: D row = mt*16 + (lane>>4)*4 + reg, col = ncol ----
    float* yo = ypart + (size_t)(s*NB + n)*25*VV;
    #pragma unroll
    for (int mt = 0; mt < 2; ++mt)
        #pragma unroll
        for (int t = 0; t < 4; ++t) {
            int ncol = (q*4 + t)*16 + (lane & 15);
            #pragma unroll
            for (int reg = 0; reg < 4; ++reg) {
                int row = mt*16 + (lane >> 4)*4 + reg;
                if (row < 25)
                    yo[(size_t)row*VV + ncol] = acc[mt][t][reg];
            }
        }
}

// ---------------------------------------------------------------------------
// Kernel 2: out[n,o,t,w] = sum_c conv_w[o,c]*y[c*6+t,w] + conv_b[o]*y[24,w]
// 32-w chunks, grid (16,NB) = 512 blocks (2/CU). ypart read exactly once.
// ---------------------------------------------------------------------------
__global__ __launch_bounds__(256) void expand_kernel(
    const float* __restrict__ ypart,
    const float* __restrict__ conv_w,
    const float* __restrict__ conv_b,
    float*       __restrict__ out)
{
    __shared__ float ysm[25][32];
    __shared__ float wsm[COUT*CIN];
    __shared__ float bsm[COUT];

    int wc = blockIdx.x;                 // 16 w-chunks of 32
    int n  = blockIdx.y;
    int tid = threadIdx.x;

    if (tid < COUT*CIN) wsm[tid] = conv_w[tid];
    if (tid < COUT)     bsm[tid] = conv_b[tid];

    // stage + reduce splits: 25*32 = 800 floats as 200 float4
    for (int l4 = tid; l4 < 200; l4 += 256) {
        int r = l4 >> 3, w8 = l4 & 7;
        float4 a = {0.f, 0.f, 0.f, 0.f};
        #pragma unroll
        for (int s = 0; s < SPLITS; ++s) {
            float4 v = *(const float4*)(ypart +
                ((size_t)(s*NB + n)*25 + r)*VV + wc*32 + w8*4);
            a.x += v.x; a.y += v.y; a.z += v.z; a.w += v.w;
        }
        *(float4*)&ysm[r][w8*4] = a;
    }
    __syncthreads();

    int w  = tid & 31;
    int og = tid >> 5;                   // 8 groups x 8 o

    float y[25];
    #pragma unroll
    for (int r = 0; r < 25; ++r) y[r] = ysm[r][w];

    #pragma unroll
    for (int oo = 0; oo < 8; ++oo) {
        int o = og*8 + oo;
        float wb[CIN];
        #pragma unroll
        for (int c = 0; c < CIN; ++c) wb[c] = wsm[o*CIN + c];
        float bo = bsm[o];
        #pragma unroll
        for (int t = 0; t < TT; ++t) {
            float val = bo * y[24];
            #pragma unroll
            for (int c = 0; c < CIN; ++c) val = fmaf(wb[c], y[c*TT + t], val);
            out[((size_t)(n*COUT + o)*TT + t)*VV + wc*32 + w] = val;
        }
    }
}

// ---------------------------------------------------------------------------
extern "C" void kernel_launch(void* const* d_in, const int* in_sizes, int n_in,
                              void* d_out, int out_size, void* d_ws, size_t ws_size,
                              hipStream_t stream)
{
    const float* x      = (const float*)d_in[0];
    const int*   A      = (const int*)  d_in[1];
    const float* conv_w = (const float*)d_in[2];
    const float* conv_b = (const float*)d_in[3];
    const float* l2_w   = (const float*)d_in[4];
    const float* l2_b   = (const float*)d_in[5];
    const float* l1_w   = (const float*)d_in[6];
    const float* l1_b   = (const float*)d_in[7];

    float* out = (float*)d_out;
    float* pP  = out + P_OFF;              // p region of d_out
    float* yp  = (float*)d_ws;             // SPLITS*NB*25*VV f32 = 13.1 MB

    dim3 gf(SPLITS, NB);                   // 256 blocks x 512 thr
    fused_kernel<<<gf, 512, 0, stream>>>(x, A, conv_w, conv_b, l2_w, l2_b,
                                         l1_w, l1_b, pP, yp);

    dim3 ge(16, NB);                       // 512 blocks
    expand_kernel<<<ge, 256, 0, stream>>>(yp, conv_w, conv_b, out);
}